// Round 3
// baseline (287.197 us; speedup 1.0000x reference)
//
#include <hip/hip_runtime.h>

typedef __bf16 bf16;
typedef __bf16 bf16x8_t __attribute__((ext_vector_type(8)));
typedef __bf16 bf16x4_t __attribute__((ext_vector_type(4)));
typedef __bf16 bf16x2_t __attribute__((ext_vector_type(2)));
typedef float f32x4_t __attribute__((ext_vector_type(4)));

#define S_ 2048
#define E_ 1024
#define HD 64
#define LOG2E 1.4426950408889634f
#define QSCALE (0.125f * LOG2E)   // 1/sqrt(64) * log2(e), folded into Q

// async global->LDS, 16B per lane; LDS dest is wave-uniform base + lane*16
__device__ __forceinline__ void gl_lds16(const bf16* g, bf16* l) {
  __builtin_amdgcn_global_load_lds(
      (const __attribute__((address_space(1))) unsigned int*)g,
      (__attribute__((address_space(3))) unsigned int*)l, 16, 0, 0);
}

// ---------- fp32 -> bf16 convert (x) ----------
__global__ void cvt4(const float* __restrict__ in, bf16* __restrict__ out) {
  int i = (blockIdx.x * 256 + threadIdx.x) * 4;
  float4 v = *(const float4*)(in + i);
  bf16x4_t o = { (bf16)v.x, (bf16)v.y, (bf16)v.z, (bf16)v.w };
  *(bf16x4_t*)(out + i) = o;
}

// ---------- fp32 [R][C] -> bf16 [C][R] (weights) ----------
__global__ void transpose_cvt(const float* __restrict__ in, bf16* __restrict__ out,
                              int R, int C) {
  __shared__ float tile[32][33];
  int c0 = blockIdx.x * 32, r0 = blockIdx.y * 32;
  int tx = threadIdx.x & 31, ty = threadIdx.x >> 5;
#pragma unroll
  for (int i = 0; i < 32; i += 8)
    tile[ty + i][tx] = in[(size_t)(r0 + ty + i) * C + c0 + tx];
  __syncthreads();
#pragma unroll
  for (int i = 0; i < 32; i += 8)
    out[(size_t)(c0 + ty + i) * R + r0 + tx] = (bf16)tile[tx][ty + i];
}

// ---------- 128x128-tile GEMM, BK=64, global_load_lds staging, XOR-swizzled LDS ----
// MODE 0: QKV epilogue (scatter to Q scaled, K, Vt transposed). MODE 1: proj fp32 out.
template <int MODE>
__global__ __launch_bounds__(256, 3)
void gemm128(const bf16* __restrict__ A, const bf16* __restrict__ Bt,
             const float* __restrict__ bias,
             bf16* __restrict__ Q, bf16* __restrict__ K, bf16* __restrict__ Vt,
             float* __restrict__ Out) {
  __shared__ __align__(16) bf16 As[128 * 64];
  __shared__ __align__(16) bf16 Bs[128 * 64];
  const int tid = threadIdx.x;
  const int wave = tid >> 6, lane = tid & 63;
  const int quad = lane >> 4, l16 = lane & 15;
  const int wm = wave >> 1, wn = wave & 1;
  const int bm = blockIdx.x, bn = blockIdx.y;

  f32x4_t acc[4][4];
#pragma unroll
  for (int i = 0; i < 4; i++)
#pragma unroll
    for (int j = 0; j < 4; j++) acc[i][j] = (f32x4_t){0.f, 0.f, 0.f, 0.f};

  for (int k0 = 0; k0 < 1024; k0 += 64) {
    __syncthreads();
#pragma unroll
    for (int it = 0; it < 4; it++) {
      int id = it * 256 + tid;
      int row = id >> 3, c = id & 7;
      int sc = (c ^ (row & 7)) * 8;
      gl_lds16(A + (size_t)(bm * 128 + row) * 1024 + k0 + sc, As + id * 8);
      gl_lds16(Bt + (size_t)(bn * 128 + row) * 1024 + k0 + sc, Bs + id * 8);
    }
    __syncthreads();
#pragma unroll
    for (int ks = 0; ks < 2; ks++) {
      bf16x8_t af[4], bfr[4];
#pragma unroll
      for (int i = 0; i < 4; i++) {
        int row = wm * 64 + i * 16 + l16;
        af[i] = *(const bf16x8_t*)&As[row * 64 + (((ks * 4 + quad) ^ (row & 7)) * 8)];
      }
#pragma unroll
      for (int j = 0; j < 4; j++) {
        int row = wn * 64 + j * 16 + l16;
        bfr[j] = *(const bf16x8_t*)&Bs[row * 64 + (((ks * 4 + quad) ^ (row & 7)) * 8)];
      }
#pragma unroll
      for (int i = 0; i < 4; i++)
#pragma unroll
        for (int j = 0; j < 4; j++)
          acc[i][j] = __builtin_amdgcn_mfma_f32_16x16x32_bf16(af[i], bfr[j], acc[i][j], 0, 0, 0);
    }
  }

  if (MODE == 0) {
#pragma unroll
    for (int j = 0; j < 4; j++) {
      int n_g = bn * 128 + wn * 64 + j * 16 + l16;
      float bv = bias[n_g];
      int which = n_g >> 10;
      int cc = n_g & 1023;
      int hh = cc >> 6, dd = cc & 63;
#pragma unroll
      for (int i = 0; i < 4; i++) {
        int m0 = bm * 128 + wm * 64 + i * 16 + quad * 4;
        int bb = m0 >> 11, ss0 = m0 & 2047;
        int bhn = bb * 16 + hh;
        if (which == 2) {
          bf16x4_t pk;
#pragma unroll
          for (int r = 0; r < 4; r++) pk[r] = (bf16)(acc[i][j][r] + bv);
          *(bf16x4_t*)&Vt[((size_t)bhn * 64 + dd) * 2048 + ss0] = pk;
        } else {
          bf16* dst = (which == 0) ? Q : K;
          float scl = (which == 0) ? QSCALE : 1.f;
#pragma unroll
          for (int r = 0; r < 4; r++)
            dst[((size_t)bhn * 2048 + ss0 + r) * 64 + dd] = (bf16)((acc[i][j][r] + bv) * scl);
        }
      }
    }
  } else {
#pragma unroll
    for (int j = 0; j < 4; j++) {
      int n_g = bn * 128 + wn * 64 + j * 16 + l16;
      float bv = bias[n_g];
#pragma unroll
      for (int i = 0; i < 4; i++) {
        int m0 = bm * 128 + wm * 64 + i * 16 + quad * 4;
#pragma unroll
        for (int r = 0; r < 4; r++)
          Out[(size_t)(m0 + r) * 1024 + n_g] = acc[i][j][r] + bv;
      }
    }
  }
}

// ---------- Flash attention, S^T formulation, half-tile softmax ----------
// Block = 256 thr (4 waves); q-blocks pid and 15-pid (uniform 17 staging iters).
// Each 128-k tile processed as two 64-k halves (sacc 32 regs; diag upper half
// skipped by waves 0,1). P round-trips through a per-wave [16q][32k] b32 buffer
// with 17-word row stride (odd stride -> ~2-way banks, i.e. free).
__global__ __launch_bounds__(256, 4)
void attn_kernel(const bf16* __restrict__ Q, const bf16* __restrict__ K,
                 const bf16* __restrict__ Vt, bf16* __restrict__ O) {
  __shared__ __align__(16) bf16 Ks[128 * 64];    // [k][d]  16KB
  __shared__ __align__(16) bf16 Vs[64 * 128];    // [d][s]  16KB
  __shared__ int Ps[4 * 272];                    // per-wave 16 rows x 17 words
  const int tid = threadIdx.x;
  const int wave = tid >> 6, lane = tid & 63;
  const int quad = lane >> 4, l16 = lane & 15;
  const int pid = blockIdx.x, bh = blockIdx.y;
  const int b = bh >> 4, h = bh & 15;

  const bf16* Qg = Q + (size_t)bh * S_ * HD;
  const bf16* Kg = K + (size_t)bh * S_ * HD;
  const bf16* Vg = Vt + (size_t)bh * HD * S_;
  int* Pw = Ps + wave * 272;

  for (int qi = 0; qi < 2; qi++) {
    const int qb = qi ? (15 - pid) : pid;
    bf16x8_t qf[2][2];
#pragma unroll
    for (int ni = 0; ni < 2; ni++)
#pragma unroll
      for (int ks = 0; ks < 2; ks++)
        qf[ni][ks] = *(const bf16x8_t*)(Qg +
            (size_t)(qb * 128 + wave * 32 + ni * 16 + l16) * HD + ks * 32 + quad * 8);

    f32x4_t o[4][2];
#pragma unroll
    for (int mi = 0; mi < 4; mi++)
#pragma unroll
      for (int ni = 0; ni < 2; ni++) o[mi][ni] = (f32x4_t){0.f, 0.f, 0.f, 0.f};
    float m_[2] = {-1e30f, -1e30f}, l_[2] = {0.f, 0.f};

    for (int kb = 0; kb <= qb; kb++) {
      __syncthreads();  // prior Ks/Vs reads done
      const bf16* Ksrc = Kg + (size_t)kb * 128 * HD;
#pragma unroll
      for (int it = 0; it < 4; it++) {
        int id = it * 256 + tid;
        {
          int row = id >> 3, c = id & 7;
          gl_lds16(Ksrc + row * 64 + ((c ^ (row & 7)) * 8), Ks + id * 8);
        }
        {
          int d = id >> 4, c = id & 15;
          gl_lds16(Vg + (size_t)d * S_ + kb * 128 + ((c ^ (d & 7)) * 8), Vs + id * 8);
        }
      }
      __syncthreads();  // staging complete

      const bool diag = (kb == qb);
#pragma unroll
      for (int hh = 0; hh < 2; hh++) {
        if (diag && hh == 1 && wave < 2) continue;  // fully-masked half (wave-uniform)

        // S^T = K·Q^T for this 64-k half: lane holds S^T[k][q=ni*16+l16]
        f32x4_t sacc[4][2];
#pragma unroll
        for (int mi = 0; mi < 4; mi++)
#pragma unroll
          for (int ni = 0; ni < 2; ni++) sacc[mi][ni] = (f32x4_t){0.f, 0.f, 0.f, 0.f};
#pragma unroll
        for (int ks = 0; ks < 2; ks++)
#pragma unroll
          for (int mi = 0; mi < 4; mi++) {
            int kr = hh * 64 + mi * 16 + l16;
            bf16x8_t kf = *(const bf16x8_t*)&Ks[kr * 64 + (((ks * 4 + quad) ^ (kr & 7)) * 8)];
            sacc[mi][0] = __builtin_amdgcn_mfma_f32_16x16x32_bf16(kf, qf[0][ks], sacc[mi][0], 0, 0, 0);
            sacc[mi][1] = __builtin_amdgcn_mfma_f32_16x16x32_bf16(kf, qf[1][ks], sacc[mi][1], 0, 0, 0);
          }

        if (diag) {
#pragma unroll
          for (int mi = 0; mi < 4; mi++)
#pragma unroll
            for (int ni = 0; ni < 2; ni++) {
              int qrow = wave * 32 + ni * 16 + l16;
              int krow = hh * 64 + mi * 16 + quad * 4;
#pragma unroll
              for (int r = 0; r < 4; r++)
                if (krow + r > qrow) sacc[mi][ni][r] = -1e30f;
            }
        }

        // online softmax (base-2, scale pre-folded into Q)
#pragma unroll
        for (int ni = 0; ni < 2; ni++) {
          float mx = -1e30f;
#pragma unroll
          for (int mi = 0; mi < 4; mi++)
#pragma unroll
            for (int r = 0; r < 4; r++) mx = fmaxf(mx, sacc[mi][ni][r]);
          mx = fmaxf(mx, __shfl_xor(mx, 16));
          mx = fmaxf(mx, __shfl_xor(mx, 32));
          float mnew = fmaxf(m_[ni], mx);
          float alpha = __builtin_amdgcn_exp2f(m_[ni] - mnew);
          m_[ni] = mnew;
          float rs = 0.f;
#pragma unroll
          for (int mi = 0; mi < 4; mi++)
#pragma unroll
            for (int r = 0; r < 4; r++) {
              float p = __builtin_amdgcn_exp2f(sacc[mi][ni][r] - mnew);
              sacc[mi][ni][r] = p;
              rs += p;
            }
          rs += __shfl_xor(rs, 16);
          rs += __shfl_xor(rs, 32);
          l_[ni] = alpha * l_[ni] + rs;
#pragma unroll
          for (int mi = 0; mi < 4; mi++)
#pragma unroll
            for (int r = 0; r < 4; r++) o[mi][ni][r] *= alpha;
        }

        // P -> per-wave LDS [16q][32k] (stride 17 words) in 32-k chunks; PV MFMA
#pragma unroll
        for (int ks2 = 0; ks2 < 2; ks2++) {
          bf16x8_t vb[4];
#pragma unroll
          for (int mi = 0; mi < 4; mi++) {
            int d = mi * 16 + l16;
            vb[mi] = *(const bf16x8_t*)&Vs[d * 128 + (((hh * 8 + ks2 * 4 + quad) ^ (d & 7)) * 8)];
          }
#pragma unroll
          for (int ni = 0; ni < 2; ni++) {
#pragma unroll
            for (int m01 = 0; m01 < 2; m01++) {
              int smi = ks2 * 2 + m01;
              bf16x2_t w0 = { (bf16)sacc[smi][ni][0], (bf16)sacc[smi][ni][1] };
              bf16x2_t w1 = { (bf16)sacc[smi][ni][2], (bf16)sacc[smi][ni][3] };
              int cw = m01 * 8 + quad * 2;
              Pw[l16 * 17 + cw]     = __builtin_bit_cast(int, w0);
              Pw[l16 * 17 + cw + 1] = __builtin_bit_cast(int, w1);
            }
            int4 rw;
            rw.x = Pw[l16 * 17 + quad * 4 + 0];
            rw.y = Pw[l16 * 17 + quad * 4 + 1];
            rw.z = Pw[l16 * 17 + quad * 4 + 2];
            rw.w = Pw[l16 * 17 + quad * 4 + 3];
            bf16x8_t pa = __builtin_bit_cast(bf16x8_t, rw);
#pragma unroll
            for (int mi = 0; mi < 4; mi++)
              o[mi][ni] = __builtin_amdgcn_mfma_f32_16x16x32_bf16(vb[mi], pa, o[mi][ni], 0, 0, 0);
          }
        }
      }
    }

    // epilogue: O^T lane layout -> O[b][s][h*64+d]
#pragma unroll
    for (int ni = 0; ni < 2; ni++) {
      float inv = 1.0f / l_[ni];
      int q_g = qb * 128 + wave * 32 + ni * 16 + l16;
      size_t rowb = (size_t)(b * S_ + q_g) * E_ + h * HD;
#pragma unroll
      for (int mi = 0; mi < 4; mi++) {
        bf16x4_t ov;
#pragma unroll
        for (int r = 0; r < 4; r++) ov[r] = (bf16)(o[mi][ni][r] * inv);
        *(bf16x4_t*)&O[rowb + mi * 16 + quad * 4] = ov;
      }
    }
  }
}

extern "C" void kernel_launch(void* const* d_in, const int* in_sizes, int n_in,
                              void* d_out, int out_size, void* d_ws, size_t ws_size,
                              hipStream_t stream) {
  const float* x      = (const float*)d_in[0];
  const float* W_attn = (const float*)d_in[1];
  const float* b_attn = (const float*)d_in[2];
  const float* W_proj = (const float*)d_in[3];
  const float* b_proj = (const float*)d_in[4];
  float* out = (float*)d_out;

  bf16* xb  = (bf16*)d_ws;            // 8192*1024
  bf16* Wat = xb + 8388608ull;        // 3072*1024 (W_attn^T)
  bf16* Wpt = Wat + 3145728ull;       // 1024*1024 (W_proj^T)
  bf16* Qb  = Wpt + 1048576ull;       // [B,H,S,64], pre-scaled by QSCALE
  bf16* Kb  = Qb + 8388608ull;        // [B,H,S,64]
  bf16* Vtb = Kb + 8388608ull;        // [B,H,64,S]
  bf16* AOb = xb;                     // alias: x dead after QKV GEMM

  cvt4<<<8192, 256, 0, stream>>>(x, xb);
  transpose_cvt<<<dim3(96, 32), 256, 0, stream>>>(W_attn, Wat, 1024, 3072);
  transpose_cvt<<<dim3(32, 32), 256, 0, stream>>>(W_proj, Wpt, 1024, 1024);
  gemm128<0><<<dim3(64, 24), 256, 0, stream>>>(xb, Wat, b_attn, Qb, Kb, Vtb, nullptr);
  attn_kernel<<<dim3(8, 64), 256, 0, stream>>>(Qb, Kb, Vtb, AOb);
  gemm128<1><<<dim3(64, 8), 256, 0, stream>>>(AOb, Wpt, b_proj, nullptr, nullptr, nullptr, out);
}

// Round 4
// 282.000 us; speedup vs baseline: 1.0184x; 1.0184x over previous
//
#include <hip/hip_runtime.h>

typedef __bf16 bf16;
typedef __bf16 bf16x8_t __attribute__((ext_vector_type(8)));
typedef __bf16 bf16x4_t __attribute__((ext_vector_type(4)));
typedef __bf16 bf16x2_t __attribute__((ext_vector_type(2)));
typedef float f32x4_t __attribute__((ext_vector_type(4)));

#define S_ 2048
#define E_ 1024
#define HD 64
#define LOG2E 1.4426950408889634f
#define QSCALE (0.125f * LOG2E)   // 1/sqrt(64) * log2(e), folded into Q

// async global->LDS, 16B per lane; LDS dest is wave-uniform base + lane*16
__device__ __forceinline__ void gl_lds16(const bf16* g, bf16* l) {
  __builtin_amdgcn_global_load_lds(
      (const __attribute__((address_space(1))) unsigned int*)g,
      (__attribute__((address_space(3))) unsigned int*)l, 16, 0, 0);
}

// ---------- fp32 -> bf16 convert (x) ----------
__global__ void cvt4(const float* __restrict__ in, bf16* __restrict__ out) {
  int i = (blockIdx.x * 256 + threadIdx.x) * 4;
  float4 v = *(const float4*)(in + i);
  bf16x4_t o = { (bf16)v.x, (bf16)v.y, (bf16)v.z, (bf16)v.w };
  *(bf16x4_t*)(out + i) = o;
}

// ---------- fp32 [R][C] -> bf16 [C][R] (weights) ----------
__global__ void transpose_cvt(const float* __restrict__ in, bf16* __restrict__ out,
                              int R, int C) {
  __shared__ float tile[32][33];
  int c0 = blockIdx.x * 32, r0 = blockIdx.y * 32;
  int tx = threadIdx.x & 31, ty = threadIdx.x >> 5;
#pragma unroll
  for (int i = 0; i < 32; i += 8)
    tile[ty + i][tx] = in[(size_t)(r0 + ty + i) * C + c0 + tx];
  __syncthreads();
#pragma unroll
  for (int i = 0; i < 32; i += 8)
    out[(size_t)(c0 + ty + i) * R + r0 + tx] = (bf16)tile[tx][ty + i];
}

// ---------- 128x128-tile GEMM, BK=64, global_load_lds staging, XOR-swizzled LDS ----
// MODE 0: QKV epilogue (scatter to Q scaled, K, Vt transposed). MODE 1: proj fp32 out.
template <int MODE>
__global__ __launch_bounds__(256, 3)
void gemm128(const bf16* __restrict__ A, const bf16* __restrict__ Bt,
             const float* __restrict__ bias,
             bf16* __restrict__ Q, bf16* __restrict__ K, bf16* __restrict__ Vt,
             float* __restrict__ Out) {
  __shared__ __align__(16) bf16 As[128 * 64];
  __shared__ __align__(16) bf16 Bs[128 * 64];
  const int tid = threadIdx.x;
  const int wave = tid >> 6, lane = tid & 63;
  const int quad = lane >> 4, l16 = lane & 15;
  const int wm = wave >> 1, wn = wave & 1;
  const int bm = blockIdx.x, bn = blockIdx.y;

  f32x4_t acc[4][4];
#pragma unroll
  for (int i = 0; i < 4; i++)
#pragma unroll
    for (int j = 0; j < 4; j++) acc[i][j] = (f32x4_t){0.f, 0.f, 0.f, 0.f};

  for (int k0 = 0; k0 < 1024; k0 += 64) {
    __syncthreads();
#pragma unroll
    for (int it = 0; it < 4; it++) {
      int id = it * 256 + tid;
      int row = id >> 3, c = id & 7;
      int sc = (c ^ (row & 7)) * 8;
      gl_lds16(A + (size_t)(bm * 128 + row) * 1024 + k0 + sc, As + id * 8);
      gl_lds16(Bt + (size_t)(bn * 128 + row) * 1024 + k0 + sc, Bs + id * 8);
    }
    __syncthreads();
#pragma unroll
    for (int ks = 0; ks < 2; ks++) {
      bf16x8_t af[4], bfr[4];
#pragma unroll
      for (int i = 0; i < 4; i++) {
        int row = wm * 64 + i * 16 + l16;
        af[i] = *(const bf16x8_t*)&As[row * 64 + (((ks * 4 + quad) ^ (row & 7)) * 8)];
      }
#pragma unroll
      for (int j = 0; j < 4; j++) {
        int row = wn * 64 + j * 16 + l16;
        bfr[j] = *(const bf16x8_t*)&Bs[row * 64 + (((ks * 4 + quad) ^ (row & 7)) * 8)];
      }
#pragma unroll
      for (int i = 0; i < 4; i++)
#pragma unroll
        for (int j = 0; j < 4; j++)
          acc[i][j] = __builtin_amdgcn_mfma_f32_16x16x32_bf16(af[i], bfr[j], acc[i][j], 0, 0, 0);
    }
  }

  if (MODE == 0) {
#pragma unroll
    for (int j = 0; j < 4; j++) {
      int n_g = bn * 128 + wn * 64 + j * 16 + l16;
      float bv = bias[n_g];
      int which = n_g >> 10;
      int cc = n_g & 1023;
      int hh = cc >> 6, dd = cc & 63;
#pragma unroll
      for (int i = 0; i < 4; i++) {
        int m0 = bm * 128 + wm * 64 + i * 16 + quad * 4;
        int bb = m0 >> 11, ss0 = m0 & 2047;
        int bhn = bb * 16 + hh;
        if (which == 2) {
          bf16x4_t pk;
#pragma unroll
          for (int r = 0; r < 4; r++) pk[r] = (bf16)(acc[i][j][r] + bv);
          *(bf16x4_t*)&Vt[((size_t)bhn * 64 + dd) * 2048 + ss0] = pk;
        } else {
          bf16* dst = (which == 0) ? Q : K;
          float scl = (which == 0) ? QSCALE : 1.f;
#pragma unroll
          for (int r = 0; r < 4; r++)
            dst[((size_t)bhn * 2048 + ss0 + r) * 64 + dd] = (bf16)((acc[i][j][r] + bv) * scl);
        }
      }
    }
  } else {
#pragma unroll
    for (int j = 0; j < 4; j++) {
      int n_g = bn * 128 + wn * 64 + j * 16 + l16;
      float bv = bias[n_g];
#pragma unroll
      for (int i = 0; i < 4; i++) {
        int m0 = bm * 128 + wm * 64 + i * 16 + quad * 4;
#pragma unroll
        for (int r = 0; r < 4; r++)
          Out[(size_t)(m0 + r) * 1024 + n_g] = acc[i][j][r] + bv;
      }
    }
  }
}

// ---------- Flash attention, S^T formulation, half-tile softmax ----------
// Grid (16, 64): qb = 15 - blockIdx.x (longest blocks first, backfilled tail).
// Wave owns 32 q rows. 128-k staging tile, processed as two 64-k halves
// (sacc[4][2] keeps natural VGPR ~130; diag upper half skipped by waves 0,1).
// P round-trip: per-wave [32 q][64 k] LDS, 36-WORD row stride -> ideal bank
// spread on both the int2 writes (4 words/bank) and int4 reads (8 words/bank).
// launch_bounds(256,3): cap 168 regs (no round-3 spill), LDS 50 KB -> 3 blk/CU.
__global__ __launch_bounds__(256, 3)
void attn_kernel(const bf16* __restrict__ Q, const bf16* __restrict__ K,
                 const bf16* __restrict__ Vt, bf16* __restrict__ O) {
  __shared__ __align__(16) bf16 Ks[128 * 64];    // [k][d]  16KB
  __shared__ __align__(16) bf16 Vs[64 * 128];    // [d][s]  16KB
  __shared__ __align__(16) int Ps[4][32 * 36];   // per-wave P, 18KB
  const int tid = threadIdx.x;
  const int wave = tid >> 6, lane = tid & 63;
  const int quad = lane >> 4, l16 = lane & 15;
  const int qb = 15 - blockIdx.x, bh = blockIdx.y;
  const int b = bh >> 4, h = bh & 15;

  const bf16* Qg = Q + (size_t)bh * S_ * HD;
  const bf16* Kg = K + (size_t)bh * S_ * HD;
  const bf16* Vg = Vt + (size_t)bh * HD * S_;
  int* Pw = &Ps[wave][0];

  // Q fragments (B-operand): n = q row (l16), k = d
  bf16x8_t qf[2][2];
#pragma unroll
  for (int ni = 0; ni < 2; ni++)
#pragma unroll
    for (int ks = 0; ks < 2; ks++)
      qf[ni][ks] = *(const bf16x8_t*)(Qg +
          (size_t)(qb * 128 + wave * 32 + ni * 16 + l16) * HD + ks * 32 + quad * 8);

  f32x4_t o[4][2];
#pragma unroll
  for (int mi = 0; mi < 4; mi++)
#pragma unroll
    for (int ni = 0; ni < 2; ni++) o[mi][ni] = (f32x4_t){0.f, 0.f, 0.f, 0.f};
  float m_[2] = {-1e30f, -1e30f}, l_[2] = {0.f, 0.f};

  for (int kb = 0; kb <= qb; kb++) {
    __syncthreads();  // prior Ks/Vs reads done
    const bf16* Ksrc = Kg + (size_t)kb * 128 * HD;
#pragma unroll
    for (int it = 0; it < 4; it++) {
      int id = it * 256 + tid;
      {
        int row = id >> 3, c = id & 7;
        gl_lds16(Ksrc + row * 64 + ((c ^ (row & 7)) * 8), Ks + id * 8);
      }
      {
        int d = id >> 4, c = id & 15;
        gl_lds16(Vg + (size_t)d * S_ + kb * 128 + ((c ^ (d & 7)) * 8), Vs + id * 8);
      }
    }
    __syncthreads();  // staging complete

    const bool diag = (kb == qb);
#pragma unroll
    for (int hh = 0; hh < 2; hh++) {
      if (diag && hh == 1 && wave < 2) continue;  // fully-masked half (wave-uniform)

      // S^T = K·Q^T for this 64-k half: lane holds S^T[k][q=ni*16+l16]
      f32x4_t sacc[4][2];
#pragma unroll
      for (int mi = 0; mi < 4; mi++)
#pragma unroll
        for (int ni = 0; ni < 2; ni++) sacc[mi][ni] = (f32x4_t){0.f, 0.f, 0.f, 0.f};
#pragma unroll
      for (int ks = 0; ks < 2; ks++)
#pragma unroll
        for (int mi = 0; mi < 4; mi++) {
          int kr = hh * 64 + mi * 16 + l16;
          bf16x8_t kf = *(const bf16x8_t*)&Ks[kr * 64 + (((ks * 4 + quad) ^ (kr & 7)) * 8)];
          sacc[mi][0] = __builtin_amdgcn_mfma_f32_16x16x32_bf16(kf, qf[0][ks], sacc[mi][0], 0, 0, 0);
          sacc[mi][1] = __builtin_amdgcn_mfma_f32_16x16x32_bf16(kf, qf[1][ks], sacc[mi][1], 0, 0, 0);
        }

      if (diag) {
#pragma unroll
        for (int mi = 0; mi < 4; mi++)
#pragma unroll
          for (int ni = 0; ni < 2; ni++) {
            int qrow = wave * 32 + ni * 16 + l16;
            int krow = hh * 64 + mi * 16 + quad * 4;
#pragma unroll
            for (int r = 0; r < 4; r++)
              if (krow + r > qrow) sacc[mi][ni][r] = -1e30f;
          }
      }

      // online softmax (base-2, scale pre-folded into Q)
#pragma unroll
      for (int ni = 0; ni < 2; ni++) {
        float mx = -1e30f;
#pragma unroll
        for (int mi = 0; mi < 4; mi++)
#pragma unroll
          for (int r = 0; r < 4; r++) mx = fmaxf(mx, sacc[mi][ni][r]);
        mx = fmaxf(mx, __shfl_xor(mx, 16));
        mx = fmaxf(mx, __shfl_xor(mx, 32));
        float mnew = fmaxf(m_[ni], mx);
        float alpha = __builtin_amdgcn_exp2f(m_[ni] - mnew);
        m_[ni] = mnew;
        float rs = 0.f;
#pragma unroll
        for (int mi = 0; mi < 4; mi++)
#pragma unroll
          for (int r = 0; r < 4; r++) {
            float p = __builtin_amdgcn_exp2f(sacc[mi][ni][r] - mnew);
            sacc[mi][ni][r] = p;
            rs += p;
          }
        rs += __shfl_xor(rs, 16);
        rs += __shfl_xor(rs, 32);
        l_[ni] = alpha * l_[ni] + rs;
#pragma unroll
        for (int mi = 0; mi < 4; mi++)
#pragma unroll
          for (int r = 0; r < 4; r++) o[mi][ni][r] *= alpha;
      }

      // P -> per-wave LDS [32 q][64 k], row stride 36 words (ideal bank spread)
#pragma unroll
      for (int ni = 0; ni < 2; ni++) {
        int qr = ni * 16 + l16;
#pragma unroll
        for (int mi = 0; mi < 4; mi++) {
          bf16x2_t w0 = { (bf16)sacc[mi][ni][0], (bf16)sacc[mi][ni][1] };
          bf16x2_t w1 = { (bf16)sacc[mi][ni][2], (bf16)sacc[mi][ni][3] };
          int2 w; w.x = __builtin_bit_cast(int, w0); w.y = __builtin_bit_cast(int, w1);
          *(int2*)&Pw[qr * 36 + mi * 8 + quad * 2] = w;
        }
      }

      // O^T += Vt · P^T over this 64-k half (2 x 32-k MFMA steps)
#pragma unroll
      for (int ks2 = 0; ks2 < 2; ks2++) {
        bf16x8_t vb[4];
#pragma unroll
        for (int mi = 0; mi < 4; mi++) {
          int d = mi * 16 + l16;
          vb[mi] = *(const bf16x8_t*)&Vs[d * 128 + (((hh * 8 + ks2 * 4 + quad) ^ (d & 7)) * 8)];
        }
#pragma unroll
        for (int ni = 0; ni < 2; ni++) {
          int4 rw = *(const int4*)&Pw[(ni * 16 + l16) * 36 + ks2 * 16 + quad * 4];
          bf16x8_t pa = __builtin_bit_cast(bf16x8_t, rw);
#pragma unroll
          for (int mi = 0; mi < 4; mi++)
            o[mi][ni] = __builtin_amdgcn_mfma_f32_16x16x32_bf16(vb[mi], pa, o[mi][ni], 0, 0, 0);
        }
      }
    }
  }

  // epilogue: O^T lane layout -> O[b][s][h*64+d]
#pragma unroll
  for (int ni = 0; ni < 2; ni++) {
    float inv = 1.0f / l_[ni];
    int q_g = qb * 128 + wave * 32 + ni * 16 + l16;
    size_t rowb = (size_t)(b * S_ + q_g) * E_ + h * HD;
#pragma unroll
    for (int mi = 0; mi < 4; mi++) {
      bf16x4_t ov;
#pragma unroll
      for (int r = 0; r < 4; r++) ov[r] = (bf16)(o[mi][ni][r] * inv);
      *(bf16x4_t*)&O[rowb + mi * 16 + quad * 4] = ov;
    }
  }
}

extern "C" void kernel_launch(void* const* d_in, const int* in_sizes, int n_in,
                              void* d_out, int out_size, void* d_ws, size_t ws_size,
                              hipStream_t stream) {
  const float* x      = (const float*)d_in[0];
  const float* W_attn = (const float*)d_in[1];
  const float* b_attn = (const float*)d_in[2];
  const float* W_proj = (const float*)d_in[3];
  const float* b_proj = (const float*)d_in[4];
  float* out = (float*)d_out;

  bf16* xb  = (bf16*)d_ws;            // 8192*1024
  bf16* Wat = xb + 8388608ull;        // 3072*1024 (W_attn^T)
  bf16* Wpt = Wat + 3145728ull;       // 1024*1024 (W_proj^T)
  bf16* Qb  = Wpt + 1048576ull;       // [B,H,S,64], pre-scaled by QSCALE
  bf16* Kb  = Qb + 8388608ull;        // [B,H,S,64]
  bf16* Vtb = Kb + 8388608ull;        // [B,H,64,S]
  bf16* AOb = xb;                     // alias: x dead after QKV GEMM

  cvt4<<<8192, 256, 0, stream>>>(x, xb);
  transpose_cvt<<<dim3(96, 32), 256, 0, stream>>>(W_attn, Wat, 1024, 3072);
  transpose_cvt<<<dim3(32, 32), 256, 0, stream>>>(W_proj, Wpt, 1024, 1024);
  gemm128<0><<<dim3(64, 24), 256, 0, stream>>>(xb, Wat, b_attn, Qb, Kb, Vtb, nullptr);
  attn_kernel<<<dim3(16, 64), 256, 0, stream>>>(Qb, Kb, Vtb, AOb);
  gemm128<1><<<dim3(64, 8), 256, 0, stream>>>(AOb, Wpt, b_proj, nullptr, nullptr, nullptr, out);
}

// Round 5
// 270.460 us; speedup vs baseline: 1.0619x; 1.0427x over previous
//
#include <hip/hip_runtime.h>

typedef __bf16 bf16;
typedef __bf16 bf16x8_t __attribute__((ext_vector_type(8)));
typedef __bf16 bf16x4_t __attribute__((ext_vector_type(4)));
typedef __bf16 bf16x2_t __attribute__((ext_vector_type(2)));
typedef float f32x4_t __attribute__((ext_vector_type(4)));
typedef float f32x16_t __attribute__((ext_vector_type(16)));

#define S_ 2048
#define E_ 1024
#define HD 64
#define LOG2E 1.4426950408889634f
#define QSCALE (0.125f * LOG2E)   // 1/sqrt(64) * log2(e), folded into Q

// async global->LDS, 16B per lane
__device__ __forceinline__ void gl_lds16(const bf16* g, bf16* l) {
  __builtin_amdgcn_global_load_lds(
      (const __attribute__((address_space(1))) unsigned int*)g,
      (__attribute__((address_space(3))) unsigned int*)l, 16, 0, 0);
}

__device__ __forceinline__ int pk2(float a, float b) {
  bf16x2_t t = { (bf16)a, (bf16)b };
  return __builtin_bit_cast(int, t);
}

// ---------- fp32 -> bf16 convert (x) ----------
__global__ void cvt4(const float* __restrict__ in, bf16* __restrict__ out) {
  int i = (blockIdx.x * 256 + threadIdx.x) * 4;
  float4 v = *(const float4*)(in + i);
  bf16x4_t o = { (bf16)v.x, (bf16)v.y, (bf16)v.z, (bf16)v.w };
  *(bf16x4_t*)(out + i) = o;
}

// ---------- fp32 [R][C] -> bf16 [C][R] (weights) ----------
__global__ void transpose_cvt(const float* __restrict__ in, bf16* __restrict__ out,
                              int R, int C) {
  __shared__ float tile[32][33];
  int c0 = blockIdx.x * 32, r0 = blockIdx.y * 32;
  int tx = threadIdx.x & 31, ty = threadIdx.x >> 5;
#pragma unroll
  for (int i = 0; i < 32; i += 8)
    tile[ty + i][tx] = in[(size_t)(r0 + ty + i) * C + c0 + tx];
  __syncthreads();
#pragma unroll
  for (int i = 0; i < 32; i += 8)
    out[(size_t)(c0 + ty + i) * R + r0 + tx] = (bf16)tile[tx][ty + i];
}

// ---------- 128x128-tile GEMM, BK=64, global_load_lds staging, XOR-swizzled LDS ----
template <int MODE>
__global__ __launch_bounds__(256, 3)
void gemm128(const bf16* __restrict__ A, const bf16* __restrict__ Bt,
             const float* __restrict__ bias,
             bf16* __restrict__ Q, bf16* __restrict__ K, bf16* __restrict__ Vt,
             float* __restrict__ Out) {
  __shared__ __align__(16) bf16 As[128 * 64];
  __shared__ __align__(16) bf16 Bs[128 * 64];
  const int tid = threadIdx.x;
  const int wave = tid >> 6, lane = tid & 63;
  const int quad = lane >> 4, l16 = lane & 15;
  const int wm = wave >> 1, wn = wave & 1;
  const int bm = blockIdx.x, bn = blockIdx.y;

  f32x4_t acc[4][4];
#pragma unroll
  for (int i = 0; i < 4; i++)
#pragma unroll
    for (int j = 0; j < 4; j++) acc[i][j] = (f32x4_t){0.f, 0.f, 0.f, 0.f};

  for (int k0 = 0; k0 < 1024; k0 += 64) {
    __syncthreads();
#pragma unroll
    for (int it = 0; it < 4; it++) {
      int id = it * 256 + tid;
      int row = id >> 3, c = id & 7;
      int sc = (c ^ (row & 7)) * 8;
      gl_lds16(A + (size_t)(bm * 128 + row) * 1024 + k0 + sc, As + id * 8);
      gl_lds16(Bt + (size_t)(bn * 128 + row) * 1024 + k0 + sc, Bs + id * 8);
    }
    __syncthreads();
#pragma unroll
    for (int ks = 0; ks < 2; ks++) {
      bf16x8_t af[4], bfr[4];
#pragma unroll
      for (int i = 0; i < 4; i++) {
        int row = wm * 64 + i * 16 + l16;
        af[i] = *(const bf16x8_t*)&As[row * 64 + (((ks * 4 + quad) ^ (row & 7)) * 8)];
      }
#pragma unroll
      for (int j = 0; j < 4; j++) {
        int row = wn * 64 + j * 16 + l16;
        bfr[j] = *(const bf16x8_t*)&Bs[row * 64 + (((ks * 4 + quad) ^ (row & 7)) * 8)];
      }
#pragma unroll
      for (int i = 0; i < 4; i++)
#pragma unroll
        for (int j = 0; j < 4; j++)
          acc[i][j] = __builtin_amdgcn_mfma_f32_16x16x32_bf16(af[i], bfr[j], acc[i][j], 0, 0, 0);
    }
  }

  if (MODE == 0) {
#pragma unroll
    for (int j = 0; j < 4; j++) {
      int n_g = bn * 128 + wn * 64 + j * 16 + l16;
      float bv = bias[n_g];
      int which = n_g >> 10;
      int cc = n_g & 1023;
      int hh = cc >> 6, dd = cc & 63;
#pragma unroll
      for (int i = 0; i < 4; i++) {
        int m0 = bm * 128 + wm * 64 + i * 16 + quad * 4;
        int bb = m0 >> 11, ss0 = m0 & 2047;
        int bhn = bb * 16 + hh;
        if (which == 2) {
          bf16x4_t pk;
#pragma unroll
          for (int r = 0; r < 4; r++) pk[r] = (bf16)(acc[i][j][r] + bv);
          *(bf16x4_t*)&Vt[((size_t)bhn * 64 + dd) * 2048 + ss0] = pk;
        } else {
          bf16* dst = (which == 0) ? Q : K;
          float scl = (which == 0) ? QSCALE : 1.f;
#pragma unroll
          for (int r = 0; r < 4; r++)
            dst[((size_t)bhn * 2048 + ss0 + r) * 64 + dd] = (bf16)((acc[i][j][r] + bv) * scl);
        }
      }
    }
  } else {
#pragma unroll
    for (int j = 0; j < 4; j++) {
      int n_g = bn * 128 + wn * 64 + j * 16 + l16;
      float bv = bias[n_g];
#pragma unroll
      for (int i = 0; i < 4; i++) {
        int m0 = bm * 128 + wm * 64 + i * 16 + quad * 4;
#pragma unroll
        for (int r = 0; r < 4; r++)
          Out[(size_t)(m0 + r) * 1024 + n_g] = acc[i][j][r] + bv;
      }
    }
  }
}

// ---------- Flash attention, 32x32 MFMA, register-resident P ----------
// Block = 128 thr (2 waves). Wave w handles 64-q tile t: w0 -> pid, w1 -> 31-pid
// (uniform 17 compute wave-iters/block). S^T = K·Q^T in 32x32x16 tiles
// (C: col=lane&31=q, row=(reg&3)+8*(reg>>2)+4*(lane>>5)=k). P^T B-frags built
// in-register via pack + shfl_xor(32) (C row group 4h <-> B k group 8h).
// O^T = V^T·P^T. LDS = Ks+Vs only (32 KB) -> 4 blocks/CU at launch_bounds(128,2).
// 1D grid, bh = blk&63 so XCD(blk%8)=bh%8: per-XCD L2 holds its 8 heads' K/V.
__global__ __launch_bounds__(128, 2)
void attn_kernel(const bf16* __restrict__ Q, const bf16* __restrict__ K,
                 const bf16* __restrict__ Vt, bf16* __restrict__ O) {
  __shared__ __align__(16) bf16 Ks[128 * 64];    // [k][d]  16KB, swizzled chunks
  __shared__ __align__(16) bf16 Vs[64 * 128];    // [d][s]  16KB, swizzled chunks
  const int tid = threadIdx.x;
  const int wave = tid >> 6, lane = tid & 63;
  const int c31 = lane & 31, h = lane >> 5;
  const int blk = blockIdx.x;
  const int bh = blk & 63, pid = blk >> 6;       // pid 0..15
  const int b = bh >> 4, hq = bh & 15;
  const int t = wave ? (31 - pid) : pid;         // 64-q tile index 0..31
  const int kmax = t >> 1;                       // this wave's last kb
  const int kend = (31 - pid) >> 1;              // block staging end
  const int q0 = t * 64;

  const bf16* Qg = Q + (size_t)bh * S_ * HD;
  const bf16* Kg = K + (size_t)bh * S_ * HD;
  const bf16* Vg = Vt + (size_t)bh * HD * S_;

  // Q B-frags: n = q = c31 (+32*ni), k = ks*16 + 8h + j
  bf16x8_t qf[2][4];
#pragma unroll
  for (int ni = 0; ni < 2; ni++)
#pragma unroll
    for (int ks = 0; ks < 4; ks++)
      qf[ni][ks] = *(const bf16x8_t*)(Qg +
          (size_t)(q0 + ni * 32 + c31) * HD + ks * 16 + h * 8);

  f32x16_t o[2][2];  // O^T [d-tile mi2][q-tile ni]
#pragma unroll
  for (int mi = 0; mi < 2; mi++)
#pragma unroll
    for (int ni = 0; ni < 2; ni++) o[mi][ni] = (f32x16_t)(0.f);
  float m_[2] = {-1e30f, -1e30f}, l_[2] = {0.f, 0.f};

  for (int kb = 0; kb <= kend; kb++) {
    __syncthreads();  // prior Ks/Vs reads done
    const bf16* Ksrc = Kg + (size_t)kb * 128 * HD;
#pragma unroll
    for (int it = 0; it < 8; it++) {
      int id = it * 128 + tid;   // 0..1023 16B chunks
      {
        int row = id >> 3, c = id & 7;
        gl_lds16(Ksrc + row * 64 + ((c ^ (row & 7)) * 8), Ks + id * 8);
      }
      {
        int d = id >> 4, c = id & 15;
        gl_lds16(Vg + (size_t)d * S_ + kb * 128 + ((c ^ (d & 7)) * 8), Vs + id * 8);
      }
    }
    __syncthreads();  // staging complete
    if (kb > kmax) continue;  // wave-uniform: this wave's tile is done

    const bool diag = (kb == kmax);
#pragma unroll
    for (int hh = 0; hh < 2; hh++) {
      if (diag && !(t & 1) && hh == 1) continue;  // fully-masked half

      // S^T = K·Q^T: 2 m-tiles (32k) x 2 n-tiles (32q), contraction d=64
      f32x16_t sa[2][2];
#pragma unroll
      for (int mi = 0; mi < 2; mi++)
#pragma unroll
        for (int ni = 0; ni < 2; ni++) sa[mi][ni] = (f32x16_t)(0.f);
#pragma unroll
      for (int ks = 0; ks < 4; ks++) {
        bf16x8_t kf[2];
#pragma unroll
        for (int mi = 0; mi < 2; mi++) {
          int krow = hh * 64 + mi * 32 + c31;
          kf[mi] = *(const bf16x8_t*)&Ks[krow * 64 + (((ks * 2 + h) ^ (krow & 7)) * 8)];
        }
#pragma unroll
        for (int mi = 0; mi < 2; mi++)
#pragma unroll
          for (int ni = 0; ni < 2; ni++)
            sa[mi][ni] = __builtin_amdgcn_mfma_f32_32x32x16_bf16(kf[mi], qf[ni][ks], sa[mi][ni], 0, 0, 0);
      }

      if (diag && (hh == 1 || !(t & 1))) {  // partial mask on this half
#pragma unroll
        for (int mi = 0; mi < 2; mi++)
#pragma unroll
          for (int ni = 0; ni < 2; ni++) {
            int ql = (t & 1) * 64 + ni * 32 + c31;
#pragma unroll
            for (int r = 0; r < 16; r++) {
              int kl = hh * 64 + mi * 32 + (r & 3) + 8 * (r >> 2) + 4 * h;
              if (kl > ql) sa[mi][ni][r] = -1e30f;
            }
          }
      }

      // online softmax per q col (in-lane over 32 k + 1 shfl across h)
#pragma unroll
      for (int ni = 0; ni < 2; ni++) {
        float mx = -1e30f;
#pragma unroll
        for (int mi = 0; mi < 2; mi++)
#pragma unroll
          for (int r = 0; r < 16; r++) mx = fmaxf(mx, sa[mi][ni][r]);
        mx = fmaxf(mx, __shfl_xor(mx, 32));
        float mnew = fmaxf(m_[ni], mx);
        float alpha = __builtin_amdgcn_exp2f(m_[ni] - mnew);
        m_[ni] = mnew;
        float rs = 0.f;
#pragma unroll
        for (int mi = 0; mi < 2; mi++)
#pragma unroll
          for (int r = 0; r < 16; r++) {
            float p = __builtin_amdgcn_exp2f(sa[mi][ni][r] - mnew);
            sa[mi][ni][r] = p;
            rs += p;
          }
        rs += __shfl_xor(rs, 32);
        l_[ni] = alpha * l_[ni] + rs;
#pragma unroll
        for (int mi = 0; mi < 2; mi++)
#pragma unroll
          for (int r = 0; r < 16; r++) o[mi][ni][r] *= alpha;
      }

      // P^T B-frags in registers + PV MFMA
#pragma unroll
      for (int mi = 0; mi < 2; mi++) {
        bf16x8_t va[2][2];  // [tt][mi2]
#pragma unroll
        for (int tt = 0; tt < 2; tt++)
#pragma unroll
          for (int mi2 = 0; mi2 < 2; mi2++) {
            int d = mi2 * 32 + c31;
            int cv = hh * 8 + (2 * mi + tt) * 2 + h;
            va[tt][mi2] = *(const bf16x8_t*)&Vs[d * 128 + ((cv ^ (d & 7)) * 8)];
          }
#pragma unroll
        for (int ni = 0; ni < 2; ni++) {
          int p[8], x[8];
#pragma unroll
          for (int w = 0; w < 8; w++) p[w] = pk2(sa[mi][ni][2 * w], sa[mi][ni][2 * w + 1]);
#pragma unroll
          for (int w = 0; w < 8; w++) x[w] = __shfl_xor(p[w], 32);
          // B-frag k-window rows 0..15 (tt=0) and 16..31 (tt=1)
          int4 w0, w1;
          if (h == 0) {
            w0 = make_int4(p[0], p[1], x[0], x[1]);
            w1 = make_int4(p[4], p[5], x[4], x[5]);
          } else {
            w0 = make_int4(x[2], x[3], p[2], p[3]);
            w1 = make_int4(x[6], x[7], p[6], p[7]);
          }
          bf16x8_t pb0 = __builtin_bit_cast(bf16x8_t, w0);
          bf16x8_t pb1 = __builtin_bit_cast(bf16x8_t, w1);
#pragma unroll
          for (int mi2 = 0; mi2 < 2; mi2++) {
            o[mi2][ni] = __builtin_amdgcn_mfma_f32_32x32x16_bf16(va[0][mi2], pb0, o[mi2][ni], 0, 0, 0);
            o[mi2][ni] = __builtin_amdgcn_mfma_f32_32x32x16_bf16(va[1][mi2], pb1, o[mi2][ni], 0, 0, 0);
          }
        }
      }
    }
  }

  // epilogue: O^T (C-layout) -> O[b][s=q][hq*64 + d]
#pragma unroll
  for (int ni = 0; ni < 2; ni++) {
    float inv = 1.0f / l_[ni];
    int q_g = q0 + ni * 32 + c31;
    size_t rowb = (size_t)(b * S_ + q_g) * E_ + hq * HD;
#pragma unroll
    for (int mi2 = 0; mi2 < 2; mi2++)
#pragma unroll
      for (int g = 0; g < 4; g++) {
        int d0 = mi2 * 32 + 8 * g + 4 * h;
        bf16x4_t ov;
#pragma unroll
        for (int r = 0; r < 4; r++) ov[r] = (bf16)(o[mi2][ni][4 * g + r] * inv);
        *(bf16x4_t*)&O[rowb + d0] = ov;
      }
  }
}

extern "C" void kernel_launch(void* const* d_in, const int* in_sizes, int n_in,
                              void* d_out, int out_size, void* d_ws, size_t ws_size,
                              hipStream_t stream) {
  const float* x      = (const float*)d_in[0];
  const float* W_attn = (const float*)d_in[1];
  const float* b_attn = (const float*)d_in[2];
  const float* W_proj = (const float*)d_in[3];
  const float* b_proj = (const float*)d_in[4];
  float* out = (float*)d_out;

  bf16* xb  = (bf16*)d_ws;            // 8192*1024
  bf16* Wat = xb + 8388608ull;        // 3072*1024 (W_attn^T)
  bf16* Wpt = Wat + 3145728ull;       // 1024*1024 (W_proj^T)
  bf16* Qb  = Wpt + 1048576ull;       // [B,H,S,64], pre-scaled by QSCALE
  bf16* Kb  = Qb + 8388608ull;        // [B,H,S,64]
  bf16* Vtb = Kb + 8388608ull;        // [B,H,64,S]
  bf16* AOb = xb;                     // alias: x dead after QKV GEMM

  cvt4<<<8192, 256, 0, stream>>>(x, xb);
  transpose_cvt<<<dim3(96, 32), 256, 0, stream>>>(W_attn, Wat, 1024, 3072);
  transpose_cvt<<<dim3(32, 32), 256, 0, stream>>>(W_proj, Wpt, 1024, 1024);
  gemm128<0><<<dim3(64, 24), 256, 0, stream>>>(xb, Wat, b_attn, Qb, Kb, Vtb, nullptr);
  attn_kernel<<<1024, 128, 0, stream>>>(Qb, Kb, Vtb, AOb);
  gemm128<1><<<dim3(64, 8), 256, 0, stream>>>(AOb, Wpt, b_proj, nullptr, nullptr, nullptr, out);
}